// Round 9
// baseline (332.013 us; speedup 1.0000x reference)
//
#include <hip/hip_runtime.h>
#include <cstdint>
#include <cstddef>

// ---------------------------------------------------------------------------
// feature_matching: corr(P=20, C=64) -> 4x (depthwise 3^3 + pointwise) blocks
//
// R25 = R24 (best: 316.7us) + DIAGNOSTIC SPLIT of fb1 and corr into halves.
//   - Problem: top-5 is saturated by fb1 iterations (~72.5); the remaining
//     ~220us (corr+fb2+fb3+fb4, each <=72) has never been profiled. Work
//     models for the tail are off by >5x; further blind theories are -EV.
//   - Split fb1 (z=8 -> 2x z=4 via b0 offset) and corr (2560 -> 2x 1280 via
//     idx0; 1280%8==0 preserves XCD band decode). Bit-identical results,
//     halves ~36/~33us -> tail kernels surface in next round's top-5 WITH
//     counters.
//   - Predict: total 315-325 (neutral). Branch on what surfaces:
//     low-util tail -> h/ci-split; high hbm_pct -> fetch diet; nothing
//     >40us -> attack transpose/launch gaps.
//
// ws layout (peak 157,286,400 B):
//   [0,        78.6MB): corrO (f16)        -> later b2o (f16, 19.7MB)
//   [78.6MB,  157.3MB): rgbT+depT (f16)    -> later b1o (f16, 78.6MB)
//                                          -> later b3o (f16, 19.7MB)
// ---------------------------------------------------------------------------

typedef unsigned short u16;
typedef _Float16 f16_t;
typedef __attribute__((ext_vector_type(2))) _Float16 half2_t;
typedef __attribute__((ext_vector_type(8))) _Float16 half8_t;
typedef __attribute__((ext_vector_type(4))) float f32x4;

static __device__ inline u16 f2h(float f) {
    union { f16_t h; u16 u; } v; v.h = (f16_t)f; return v.u;
}
static __device__ inline half2_t H2(uint32_t u) {
    union { uint32_t u; half2_t h; } v; v.u = u; return v.h;
}

#if __has_builtin(__builtin_amdgcn_fdot2)
static __device__ inline float FDOT2(half2_t a, half2_t b, float c) {
    return __builtin_amdgcn_fdot2(a, b, c, false);
}
#else
static __device__ inline float FDOT2(half2_t a, half2_t b, float c) {
    return fmaf((float)a.x, (float)b.x, fmaf((float)a.y, (float)b.y, c));
}
#endif

#if __has_builtin(__builtin_amdgcn_alignbit)
static __device__ inline uint32_t mkp(uint32_t lo, uint32_t hi) {
    return __builtin_amdgcn_alignbit(hi, lo, 16);   // (lo.hi16, hi.lo16)
}
#else
static __device__ inline uint32_t mkp(uint32_t lo, uint32_t hi) {
    return (lo >> 16) | (hi << 16);
}
#endif

static __device__ inline uint32_t ldu(const u16* p) { return *(const uint32_t*)p; }

// ---------------------------------------------------------------------------
// Prepass: (b,c,h,w) fp32 -> (b,h,w,c) f16, LDS tile transpose per (b,h).
// ---------------------------------------------------------------------------
__global__ __launch_bounds__(256) void transpose_f16(
        const float* __restrict__ rgb, const float* __restrict__ dep,
        u16* __restrict__ rgbT, u16* __restrict__ depT) {
    const int bh = blockIdx.x;
    const float* src = blockIdx.y ? dep : rgb;
    u16* dst = blockIdx.y ? depT : rgbT;
    const int tid = threadIdx.x;
    const int b = bh >> 6, h = bh & 63;

    __shared__ u16 S[64 * 194];

    const float* srcb = src + (size_t)b * 786432 + (size_t)h * 192;
#pragma unroll
    for (int it = 0; it < 12; ++it) {
        const int idx = it * 256 + tid;      // 3072 = 64c x 48 float4
        const int c = idx / 48, w4 = idx - c * 48;
        const float4 v = *(const float4*)(srcb + (size_t)c * 12288 + 4 * w4);
        u16* sp = &S[c * 194 + 4 * w4];
        sp[0] = f2h(v.x); sp[1] = f2h(v.y); sp[2] = f2h(v.z); sp[3] = f2h(v.w);
    }
    __syncthreads();
    u16* dstb = dst + (size_t)bh * 192 * 64;
#pragma unroll
    for (int it = 0; it < 12; ++it) {
        const int idx = it * 256 + tid;      // 3072 = 192w x 16 c4
        const int w = idx >> 4, c4 = idx & 15;
        ushort4 o;
        o.x = S[(4 * c4 + 0) * 194 + w];
        o.y = S[(4 * c4 + 1) * 194 + w];
        o.z = S[(4 * c4 + 2) * 194 + w];
        o.w = S[(4 * c4 + 3) * 194 + w];
        *(ushort4*)(dstb + (size_t)w * 64 + 4 * c4) = o;
    }
}

// ---------------------------------------------------------------------------
// corr v6: full-tile unconditional LDS stores, window-select at readout.
// Wave-private region: 3 t-blocks x 16 wl x 52 u (u16), 2560 u16/wave.
//   write: Lw[832t + 52(4q+r) + 16ut + n]   (t,r,ut = compile-time imms)
//   read : Lw[832t + 53wl + dj + 6]
// idx0: diagnostic split offset (1280%8==0 keeps the band decode intact).
// ---------------------------------------------------------------------------
__global__ __launch_bounds__(256) void corr_mfma(
        const u16* __restrict__ rgbT, const u16* __restrict__ depT,
        u16* __restrict__ out, int idx0) {
    const int idx = blockIdx.x + idx0;
    const int band = idx & 7;
    const int j    = idx >> 3;
    const int dig  = j % 5;
    const int rest = j / 5;          // 0..63
    const int h    = band * 8 + (rest & 7);
    const int b    = rest >> 3;
    const int tid = threadIdx.x;
    const int lane = tid & 63, wave = tid >> 6;
    const int n = lane & 15, q = lane >> 4;
    const int w0base = wave * 48;

    __shared__ u16 L[4 * 2560];
    u16* Lw = &L[wave * 2560];
    const int wb16 = q * 208 + n;    // per-thread write base (u16 units)

    const u16* Abase = rgbT + (size_t)(b * 64 + h) * 12288;
    half8_t a0[3], a1[3];
#pragma unroll
    for (int t = 0; t < 3; ++t) {
        const half8_t* Ap = (const half8_t*)(Abase + (size_t)(w0base + t * 16 + n) * 64 + q * 8);
        a0[t] = Ap[0];               // c = q*8 .. q*8+7
        a1[t] = Ap[4];               // c += 32
    }

#pragma unroll
    for (int i = 0; i < 4; ++i) {
        const int di = dig * 4 + i;
        const int hd = h + di - 10;
        const bool valid = (hd >= 0) && (hd < 64);   // block-uniform

        if (valid) {
            const u16* Bbase = depT + (size_t)(b * 64 + hd) * 12288;
            half8_t B0[5], B1[5];
#pragma unroll
            for (int k = 0; k < 5; ++k) {
                const int u0 = w0base + (k - 1) * 16;
                if (u0 >= 0 && u0 <= 176) {      // wave-uniform
                    const half8_t* Bp = (const half8_t*)(Bbase + (size_t)(u0 + n) * 64 + q * 8);
                    B0[k] = Bp[0];
                    B1[k] = Bp[4];
                } else {
                    B0[k] = (half8_t)(f16_t)0.f;
                    B1[k] = (half8_t)(f16_t)0.f;
                }
            }
#pragma unroll
            for (int t = 0; t < 3; ++t) {
                f32x4 acc[3];
#pragma unroll
                for (int ut = 0; ut < 3; ++ut) {
                    acc[ut].x = 0.f; acc[ut].y = 0.f; acc[ut].z = 0.f; acc[ut].w = 0.f;
                }
#pragma unroll
                for (int ut = 0; ut < 3; ++ut) {
                    const int k = t + ut;        // u-tile t+ut-1
                    acc[ut] = __builtin_amdgcn_mfma_f32_16x16x32_f16(a0[t], B0[k], acc[ut], 0, 0, 0);
                    acc[ut] = __builtin_amdgcn_mfma_f32_16x16x32_f16(a1[t], B1[k], acc[ut], 0, 0, 0);
                }
                // unconditional full-tile stores; t/ut/r are imm offsets
#pragma unroll
                for (int ut = 0; ut < 3; ++ut) {
#pragma unroll
                    for (int r = 0; r < 4; ++r) {
                        Lw[wb16 + t * 832 + r * 52 + ut * 16] = f2h(acc[ut][r]);
                    }
                }
            }
        }

        // readout for this di (wave-private LDS; no barrier needed)
        u16* outb = out + ((size_t)((b * 20 + di) * 20) * 64 + h) * 192;
#pragma unroll
        for (int it = 0; it < 4; ++it) {
            const int item = it * 64 + lane;
            if (item < 240) {
                const int dj  = item / 12;
                const int w4l = item - dj * 12;
                ushort4 o;
                if (valid) {
                    const int t  = w4l >> 2;
                    const int wl = (w4l & 3) * 4;
                    const int base = t * 832 + wl * 53 + dj + 6;
                    o.x = Lw[base];
                    o.y = Lw[base + 53];
                    o.z = Lw[base + 106];
                    o.w = Lw[base + 159];
                } else {
                    o = make_ushort4(0, 0, 0, 0);
                }
                *(ushort4*)(outb + (size_t)dj * 12288 + 4 * (wave * 12 + w4l)) = o;
            }
        }
    }
}

// ---------------------------------------------------------------------------
// Fused block v16: scalar row loads + generalized XCD swizzle (HT%8==0).
// b0: diagnostic batch offset for split launches.
// ---------------------------------------------------------------------------
template<int CIN, int COUT, int S, int DT, int HH, int DIN, int HIN, int WIN,
         int DO, int HO, int WO, typename TOUT, bool SWZ = false>
static __device__ __forceinline__ void fused_impl(
        const u16* __restrict__ x,
        const float* __restrict__ dw_w, const float* __restrict__ dw_b,
        const float* __restrict__ pw_w, const float* __restrict__ pw_b,
        TOUT* __restrict__ y, int b0) {
    static_assert(WO % 48 == 0 && HO % HH == 0, "tile divisibility");
    constexpr int CINP = (CIN == 20) ? 22 : 42;    // odd dword stride
    constexpr int NTASK = CIN * 12;
    constexpr int WT = WO / 48;
    constexpr int HT = HO / HH;
    constexpr int NP = S * (DT - 1) + 3;
    constexpr int ROWS = S * (HH - 1) + 3;         // 6 or 9 (HH=4)
    constexpr int NL = (S == 1) ? 4 : 5;           // dwords per row
    constexpr int G  = (ROWS % 6 == 0) ? 6 : 3;    // rows per load batch
    constexpr int NG = ROWS / G;

    int wt, ht;
    if constexpr (SWZ) {
        // XCD band decode: XCD = blockIdx.x % 8 (y/z grid strides are
        // 0 mod 8). Each XCD owns HT/8 consecutive ht rows for all wt, so
        // h-halo rows between the band's tiles stay in the local L2.
        static_assert(HT % 8 == 0, "swz needs HT%8==0");
        constexpr int HPX = HT / 8;      // ht rows per xcd
        const int xx  = blockIdx.x;
        const int xcd = xx & 7;
        const int k   = xx >> 3;         // 0 .. WT*HPX-1
        ht = xcd * HPX + k / WT;
        wt = k - (k / WT) * WT;
    } else {
        wt = blockIdx.x % WT;
        ht = blockIdx.x / WT;
    }
    const int d0 = blockIdx.y * DT;
    const int b  = blockIdx.z + b0;
    const int tid = threadIdx.x;
    const int h0 = ht * HH;
    const int wbase = wt * 48;

    __shared__ uint32_t sKW[CIN * 18];   // per ci: 9 taps x (KA,KB) half2
    __shared__ float    sDB[CIN];
    __shared__ u16      sT[DT * HH * 48 * CINP + 16];

    for (int i = tid; i < CIN * 9; i += 256) {
        const int ci = i / 9, t = i - ci * 9;
        const int kd = t / 3, kh = t - 3 * kd;
        const float k0 = dw_w[ci * 27 + kd * 9 + kh * 3 + 0];
        const float k1 = dw_w[ci * 27 + kd * 9 + kh * 3 + 1];
        const float k2 = dw_w[ci * 27 + kd * 9 + kh * 3 + 2];
        union { half2_t h; uint32_t u; } a, bb;
        a.h.x = (f16_t)k0; a.h.y = (f16_t)k1;
        if constexpr (S == 1) { bb.h.x = (f16_t)k2; bb.h.y = (f16_t)0.f; }
        else                  { bb.h.x = (f16_t)0.f; bb.h.y = (f16_t)k2; }
        sKW[ci * 18 + 2 * t]     = a.u;
        sKW[ci * 18 + 2 * t + 1] = bb.u;
    }
    for (int i = tid; i < CIN; i += 256) sDB[i] = dw_b[i];
    __syncthreads();

    // ---------------- phase 1: depthwise via fdot2 ----------------
    for (int idx = tid; idx < NTASK; idx += 256) {
        const int ci = idx / 12;
        const int wg = idx - ci * 12;
        const int w0g = wbase + wg * 4;
        const int offA = (w0g > 0) ? -2 : 0;   // keeps corner load in-bounds

        half2_t KA[9], KB[9];
#pragma unroll
        for (int t = 0; t < 9; ++t) {
            KA[t] = H2(sKW[ci * 18 + 2 * t]);       // broadcast across wg
            KB[t] = H2(sKW[ci * 18 + 2 * t + 1]);
        }

        float acc[DT][HH][4];
#pragma unroll
        for (int dl = 0; dl < DT; ++dl)
#pragma unroll
            for (int a = 0; a < HH; ++a)
#pragma unroll
                for (int c = 0; c < 4; ++c) acc[dl][a][c] = 0.f;

        const u16* plane0 = x + (size_t)(b * CIN + ci) * DIN * HIN * WIN;
#pragma unroll
        for (int p = 0; p < NP; ++p) {
            const int din = S * d0 - 1 + p;
            if (din < 0 || din >= DIN) continue;       // block-uniform, rare
            const u16* pl = plane0 + (size_t)din * HIN * WIN;
#pragma unroll
            for (int g = 0; g < NG; ++g) {
                // ---- load pass: all rows of this batch, unconditional ----
                uint32_t R[G][NL];
#pragma unroll
                for (int rr = 0; rr < G; ++rr) {
                    const int r = g * G + rr;
                    int hin = h0 * S - 1 + r;
                    int hc = hin < 0 ? 0 : (hin >= HIN ? HIN - 1 : hin);
                    const u16* rowp = pl + (size_t)hc * WIN + (size_t)w0g * S;
                    R[rr][0] = ldu(rowp + offA);
                    R[rr][1] = ldu(rowp);
                    R[rr][2] = ldu(rowp + 2);
                    R[rr][3] = ldu(rowp + 4);
                    if constexpr (S == 2) R[rr][4] = ldu(rowp + 6);
                }
                // ---- compute pass: masks + fdot2 ----
#pragma unroll
                for (int rr = 0; rr < G; ++rr) {
                    const int r = g * G + rr;
                    const int hin = h0 * S - 1 + r;
                    uint32_t D0 = R[rr][0], D1 = R[rr][1];
                    uint32_t D2 = R[rr][2], D3 = R[rr][3];
                    uint32_t E4 = 0;
                    if constexpr (S == 2) E4 = R[rr][4];
                    // w-edge masks (per-thread)
                    D0 = (w0g > 0) ? D0 : 0u;
                    if constexpr (S == 1) D3 = (w0g + 4 < WIN) ? D3 : 0u;
                    // h-validity: only boundary rows can be OOB.
                    if constexpr (S == 1) {
                        if (r == 0 || r == ROWS - 1) {
                            const bool rv = (hin >= 0) && (hin < HIN);
                            if (!rv) { D0 = 0; D1 = 0; D2 = 0; D3 = 0; }
                        }
                    } else {
                        if (r == 0) {
                            const bool rv = (hin >= 0);
                            if (!rv) { D0 = 0; D1 = 0; D2 = 0; D3 = 0; E4 = 0; }
                        }
                    }
                    uint32_t PA[4], PB[4];
                    if constexpr (S == 1) {
                        const uint32_t m01 = mkp(D0, D1);  // (x-1,x0)
                        const uint32_t m12 = mkp(D1, D2);  // (x1,x2)
                        const uint32_t m23 = mkp(D2, D3);  // (x3,x4)
                        PA[0] = m01; PA[1] = D1; PA[2] = m12; PA[3] = D2;
                        PB[0] = m12; PB[1] = D2; PB[2] = m23; PB[3] = D3;
                    } else {
                        PA[0] = mkp(D0, D1); PA[1] = mkp(D1, D2);
                        PA[2] = mkp(D2, D3); PA[3] = mkp(D3, E4);
                        PB[0] = D1; PB[1] = D2; PB[2] = D3; PB[3] = E4;
                    }
#pragma unroll
                    for (int dl = 0; dl < DT; ++dl) {
                        const int kd = p - S * dl;         // folds after unroll
                        if (kd < 0 || kd > 2) continue;
#pragma unroll
                        for (int hh = 0; hh < HH; ++hh) {
                            const int kh = r - S * hh;     // folds after unroll
                            if (kh < 0 || kh > 2) continue;
                            const int t = kd * 3 + kh;
#pragma unroll
                            for (int k = 0; k < 4; ++k)
                                acc[dl][hh][k] = FDOT2(H2(PB[k]), KB[t],
                                                 FDOT2(H2(PA[k]), KA[t],
                                                       acc[dl][hh][k]));
                        }
                    }
                }
            }
        }

        const float bia = sDB[ci];
#pragma unroll
        for (int dl = 0; dl < DT; ++dl) {
#pragma unroll
            for (int hh = 0; hh < HH; ++hh) {
#pragma unroll
                for (int k = 0; k < 4; ++k) {
                    const float t = acc[dl][hh][k] + bia;
                    sT[((dl * HH + hh) * 48 + wg * 4 + k) * CINP + ci] =
                        f2h(fmaxf(t, 0.1f * t));
                }
            }
        }
    }
    __syncthreads();

    // ---------------- phase 2: pointwise via f16 MFMA ----------------
    constexpr int NT = (COUT + 15) / 16;   // co tiles
    constexpr int KH = (CIN + 31) / 32;    // K=32 chunks
    constexpr int TOTAL_MT = DT * HH * 3;  // 16-wide M tiles
    const int lane = tid & 63, wave = tid >> 6;
    const int m15 = lane & 15, q = lane >> 4;

    half8_t bf[NT][KH];
    float   pb[NT];
#pragma unroll
    for (int nt = 0; nt < NT; ++nt) {
        const int co = nt * 16 + m15;
        pb[nt] = (co < COUT) ? pw_b[co] : 0.f;
#pragma unroll
        for (int kh = 0; kh < KH; ++kh) {
            union { half8_t v; f16_t e[8]; } u;
#pragma unroll
            for (int j = 0; j < 8; ++j) {
                const int ci = kh * 32 + q * 8 + j;
                u.e[j] = (co < COUT && ci < CIN)
                         ? (f16_t)pw_w[co * CIN + ci] : (f16_t)0.f;
            }
            bf[nt][kh] = u.v;
        }
    }

    const size_t planeSz = (size_t)DO * HO * WO;
    for (int mt = wave; mt < TOTAL_MT; mt += 4) {
        const int dl  = mt / (3 * HH);
        const int rem = mt - dl * 3 * HH;
        const int hh  = rem / 3;
        const int w0  = (rem - hh * 3) * 16;
        if (d0 + dl >= DO) continue;           // tail guard

        const int pos0 = (dl * HH + hh) * 48 + w0 + m15;
        const u16* ap = &sT[(size_t)pos0 * CINP];
        union { uint32_t u[4]; half8_t v; } af[KH];
#pragma unroll
        for (int kh = 0; kh < KH; ++kh) {
            const int ci0 = kh * 32 + q * 8;
            af[kh].u[0] = (ci0     < CIN) ? ldu(ap + ci0)     : 0u;
            af[kh].u[1] = (ci0 + 2 < CIN) ? ldu(ap + ci0 + 2) : 0u;
            af[kh].u[2] = (ci0 + 4 < CIN) ? ldu(ap + ci0 + 4) : 0u;
            af[kh].u[3] = (ci0 + 6 < CIN) ? ldu(ap + ci0 + 6) : 0u;
        }
#pragma unroll
        for (int nt = 0; nt < NT; ++nt) {
            f32x4 acc;
            acc.x = 0.f; acc.y = 0.f; acc.z = 0.f; acc.w = 0.f;
#pragma unroll
            for (int kh = 0; kh < KH; ++kh)
                acc = __builtin_amdgcn_mfma_f32_16x16x32_f16(
                          af[kh].v, bf[nt][kh], acc, 0, 0, 0);
            const int co = nt * 16 + m15;
            if (co < COUT) {
                const float bias = pb[nt];
                TOUT* yp = y + (size_t)b * COUT * planeSz + (size_t)co * planeSz
                             + (size_t)(d0 + dl) * HO * WO
                             + (size_t)(h0 + hh) * WO + wbase + w0 + q * 4;
                float s0 = acc.x + bias, s1 = acc.y + bias;
                float s2 = acc.z + bias, s3 = acc.w + bias;
                s0 = fmaxf(s0, 0.1f * s0); s1 = fmaxf(s1, 0.1f * s1);
                s2 = fmaxf(s2, 0.1f * s2); s3 = fmaxf(s3, 0.1f * s3);
                if constexpr (sizeof(TOUT) == 4) {
                    float4 o; o.x = s0; o.y = s1; o.z = s2; o.w = s3;
                    *(float4*)yp = o;
                } else {
                    ushort4 o;
                    o.x = f2h(s0); o.y = f2h(s1); o.z = f2h(s2); o.w = f2h(s3);
                    *(ushort4*)yp = o;
                }
            }
        }
    }
}

// Named wrappers -> per-stage visibility in rocprof.
__global__ __launch_bounds__(256) void fb1_dwpw(
        const u16* __restrict__ x, const float* __restrict__ dww,
        const float* __restrict__ dwb, const float* __restrict__ pww,
        const float* __restrict__ pwb, u16* __restrict__ y, int b0) {
    fused_impl<20, 20, 1, 4, 4, 20, 64, 192, 20, 64, 192, u16, true>(x, dww, dwb, pww, pwb, y, b0);
}
__global__ __launch_bounds__(256) void fb2_dwpw(
        const u16* __restrict__ x, const float* __restrict__ dww,
        const float* __restrict__ dwb, const float* __restrict__ pww,
        const float* __restrict__ pwb, u16* __restrict__ y) {
    fused_impl<20, 40, 2, 2, 4, 20, 64, 192, 10, 32, 96, u16, true>(x, dww, dwb, pww, pwb, y, 0);
}
__global__ __launch_bounds__(256) void fb3_dwpw(
        const u16* __restrict__ x, const float* __restrict__ dww,
        const float* __restrict__ dwb, const float* __restrict__ pww,
        const float* __restrict__ pwb, u16* __restrict__ y) {
    fused_impl<40, 40, 1, 2, 4, 10, 32, 96, 10, 32, 96, u16, true>(x, dww, dwb, pww, pwb, y, 0);
}
__global__ __launch_bounds__(256) void fb4_dwpw(
        const u16* __restrict__ x, const float* __restrict__ dww,
        const float* __restrict__ dwb, const float* __restrict__ pww,
        const float* __restrict__ pwb, float* __restrict__ y) {
    fused_impl<40, 80, 2, 1, 4, 10, 32, 96, 5, 16, 48, float, false>(x, dww, dwb, pww, pwb, y, 0);
}

// ---------------------------------------------------------------------------
extern "C" void kernel_launch(void* const* d_in, const int* in_sizes, int n_in,
                              void* d_out, int out_size, void* d_ws, size_t ws_size,
                              hipStream_t stream) {
    const float* rgb  = (const float*)d_in[0];
    const float* dep  = (const float*)d_in[1];
    const float* dw1w = (const float*)d_in[2];
    const float* dw1b = (const float*)d_in[3];
    const float* pw1w = (const float*)d_in[4];
    const float* pw1b = (const float*)d_in[5];
    const float* dw2w = (const float*)d_in[6];
    const float* dw2b = (const float*)d_in[7];
    const float* pw2w = (const float*)d_in[8];
    const float* pw2b = (const float*)d_in[9];
    const float* dw3w = (const float*)d_in[10];
    const float* dw3b = (const float*)d_in[11];
    const float* pw3w = (const float*)d_in[12];
    const float* pw3b = (const float*)d_in[13];
    const float* dw4w = (const float*)d_in[14];
    const float* dw4b = (const float*)d_in[15];
    const float* pw4w = (const float*)d_in[16];
    const float* pw4b = (const float*)d_in[17];

    const size_t HALF = 78643200;
    u16* corrO = (u16*)d_ws;
    u16* rgbT  = (u16*)((char*)d_ws + HALF);
    u16* depT  = (u16*)((char*)d_ws + HALF + 12582912);
    u16* b1o   = (u16*)((char*)d_ws + HALF);   // rgbT/depT dead by then
    u16* b2o   = (u16*)d_ws;                   // corrO dead by then
    u16* b3o   = (u16*)((char*)d_ws + HALF);   // b1o dead by then
    float* outp = (float*)d_out;

    transpose_f16<<<dim3(512, 2), 256, 0, stream>>>(rgb, dep, rgbT, depT);

    // diagnostic split: two half-dispatches each (bit-identical work)
    corr_mfma<<<dim3(1280), 256, 0, stream>>>(rgbT, depT, corrO, 0);
    corr_mfma<<<dim3(1280), 256, 0, stream>>>(rgbT, depT, corrO, 1280);

    fb1_dwpw<<<dim3(64, 5, 4), 256, 0, stream>>>(corrO, dw1w, dw1b, pw1w, pw1b, b1o, 0);
    fb1_dwpw<<<dim3(64, 5, 4), 256, 0, stream>>>(corrO, dw1w, dw1b, pw1w, pw1b, b1o, 4);

    fb2_dwpw<<<dim3(16, 5, 8), 256, 0, stream>>>(b1o, dw2w, dw2b, pw2w, pw2b, b2o);
    fb3_dwpw<<<dim3(16, 5, 8), 256, 0, stream>>>(b2o, dw3w, dw3b, pw3w, pw3b, b3o);
    fb4_dwpw<<<dim3(4, 5, 8), 256, 0, stream>>>(b3o, dw4w, dw4b, pw4w, pw4b, outp);
}

// Round 11
// 313.066 us; speedup vs baseline: 1.0605x; 1.0605x over previous
//
#include <hip/hip_runtime.h>
#include <cstdint>
#include <cstddef>

// ---------------------------------------------------------------------------
// feature_matching: corr(P=20, C=64) -> 4x (depthwise 3^3 + pointwise) blocks
//
// R27 = R26 resubmitted verbatim (R26 bench was an infra failure:
// "MI355X container failed twice" — kernel never evaluated).
//
// R26 = R24 restored (best, 316.7us; R25 split diagnostic cost +15 via
// occupancy/ramp loss) + corr readout widened to ushort8 (corr v7).
//   - R25 accounting: fb1 72.5, corr ~80+-6 (co-#1, halves just under the
//     43.2 top-5 cutoff), transpose ~25, fb2+3+4 ~110-130 (each <43).
//   - corr v7: readout pairs w4l=2p,2p+1 (same t-block; hi half = base+212)
//     -> 120 ushort8 stores in 2 rounds instead of 240 ushort4 in 4.
//     Same LDS reads, same values, same destinations; 16B-aligned
//     (96*wave + 16*p bytes). Bit-identical output.
//   - Predict: total ~312-315; fb1 ~72.5 top. Revert to exact R24 if >320.
//
// ws layout (peak 157,286,400 B):
//   [0,        78.6MB): corrO (f16)        -> later b2o (f16, 19.7MB)
//   [78.6MB,  157.3MB): rgbT+depT (f16)    -> later b1o (f16, 78.6MB)
//                                          -> later b3o (f16, 19.7MB)
// ---------------------------------------------------------------------------

typedef unsigned short u16;
typedef _Float16 f16_t;
typedef __attribute__((ext_vector_type(2))) _Float16 half2_t;
typedef __attribute__((ext_vector_type(8))) _Float16 half8_t;
typedef __attribute__((ext_vector_type(8))) unsigned short ushort8_t;
typedef __attribute__((ext_vector_type(4))) float f32x4;

static __device__ inline u16 f2h(float f) {
    union { f16_t h; u16 u; } v; v.h = (f16_t)f; return v.u;
}
static __device__ inline half2_t H2(uint32_t u) {
    union { uint32_t u; half2_t h; } v; v.u = u; return v.h;
}

#if __has_builtin(__builtin_amdgcn_fdot2)
static __device__ inline float FDOT2(half2_t a, half2_t b, float c) {
    return __builtin_amdgcn_fdot2(a, b, c, false);
}
#else
static __device__ inline float FDOT2(half2_t a, half2_t b, float c) {
    return fmaf((float)a.x, (float)b.x, fmaf((float)a.y, (float)b.y, c));
}
#endif

#if __has_builtin(__builtin_amdgcn_alignbit)
static __device__ inline uint32_t mkp(uint32_t lo, uint32_t hi) {
    return __builtin_amdgcn_alignbit(hi, lo, 16);   // (lo.hi16, hi.lo16)
}
#else
static __device__ inline uint32_t mkp(uint32_t lo, uint32_t hi) {
    return (lo >> 16) | (hi << 16);
}
#endif

static __device__ inline uint32_t ldu(const u16* p) { return *(const uint32_t*)p; }

// ---------------------------------------------------------------------------
// Prepass: (b,c,h,w) fp32 -> (b,h,w,c) f16, LDS tile transpose per (b,h).
// ---------------------------------------------------------------------------
__global__ __launch_bounds__(256) void transpose_f16(
        const float* __restrict__ rgb, const float* __restrict__ dep,
        u16* __restrict__ rgbT, u16* __restrict__ depT) {
    const int bh = blockIdx.x;
    const float* src = blockIdx.y ? dep : rgb;
    u16* dst = blockIdx.y ? depT : rgbT;
    const int tid = threadIdx.x;
    const int b = bh >> 6, h = bh & 63;

    __shared__ u16 S[64 * 194];

    const float* srcb = src + (size_t)b * 786432 + (size_t)h * 192;
#pragma unroll
    for (int it = 0; it < 12; ++it) {
        const int idx = it * 256 + tid;      // 3072 = 64c x 48 float4
        const int c = idx / 48, w4 = idx - c * 48;
        const float4 v = *(const float4*)(srcb + (size_t)c * 12288 + 4 * w4);
        u16* sp = &S[c * 194 + 4 * w4];
        sp[0] = f2h(v.x); sp[1] = f2h(v.y); sp[2] = f2h(v.z); sp[3] = f2h(v.w);
    }
    __syncthreads();
    u16* dstb = dst + (size_t)bh * 192 * 64;
#pragma unroll
    for (int it = 0; it < 12; ++it) {
        const int idx = it * 256 + tid;      // 3072 = 192w x 16 c4
        const int w = idx >> 4, c4 = idx & 15;
        ushort4 o;
        o.x = S[(4 * c4 + 0) * 194 + w];
        o.y = S[(4 * c4 + 1) * 194 + w];
        o.z = S[(4 * c4 + 2) * 194 + w];
        o.w = S[(4 * c4 + 3) * 194 + w];
        *(ushort4*)(dstb + (size_t)w * 64 + 4 * c4) = o;
    }
}

// ---------------------------------------------------------------------------
// corr v7: full-tile unconditional LDS stores; readout widened to ushort8.
// Wave-private region: 3 t-blocks x 16 wl x 52 u (u16), 2560 u16/wave.
//   write: Lw[832t + 52(4q+r) + 16ut + n]   (t,r,ut = compile-time imms)
//   read : Lw[832t + 53wl + dj + 6]; pair w4l=2p,2p+1 -> hi half at +212.
// ---------------------------------------------------------------------------
__global__ __launch_bounds__(256) void corr_mfma(
        const u16* __restrict__ rgbT, const u16* __restrict__ depT,
        u16* __restrict__ out) {
    const int idx = blockIdx.x;
    const int band = idx & 7;
    const int j    = idx >> 3;
    const int dig  = j % 5;
    const int rest = j / 5;          // 0..63
    const int h    = band * 8 + (rest & 7);
    const int b    = rest >> 3;
    const int tid = threadIdx.x;
    const int lane = tid & 63, wave = tid >> 6;
    const int n = lane & 15, q = lane >> 4;
    const int w0base = wave * 48;

    __shared__ u16 L[4 * 2560];
    u16* Lw = &L[wave * 2560];
    const int wb16 = q * 208 + n;    // per-thread write base (u16 units)

    const u16* Abase = rgbT + (size_t)(b * 64 + h) * 12288;
    half8_t a0[3], a1[3];
#pragma unroll
    for (int t = 0; t < 3; ++t) {
        const half8_t* Ap = (const half8_t*)(Abase + (size_t)(w0base + t * 16 + n) * 64 + q * 8);
        a0[t] = Ap[0];               // c = q*8 .. q*8+7
        a1[t] = Ap[4];               // c += 32
    }

#pragma unroll
    for (int i = 0; i < 4; ++i) {
        const int di = dig * 4 + i;
        const int hd = h + di - 10;
        const bool valid = (hd >= 0) && (hd < 64);   // block-uniform

        if (valid) {
            const u16* Bbase = depT + (size_t)(b * 64 + hd) * 12288;
            half8_t B0[5], B1[5];
#pragma unroll
            for (int k = 0; k < 5; ++k) {
                const int u0 = w0base + (k - 1) * 16;
                if (u0 >= 0 && u0 <= 176) {      // wave-uniform
                    const half8_t* Bp = (const half8_t*)(Bbase + (size_t)(u0 + n) * 64 + q * 8);
                    B0[k] = Bp[0];
                    B1[k] = Bp[4];
                } else {
                    B0[k] = (half8_t)(f16_t)0.f;
                    B1[k] = (half8_t)(f16_t)0.f;
                }
            }
#pragma unroll
            for (int t = 0; t < 3; ++t) {
                f32x4 acc[3];
#pragma unroll
                for (int ut = 0; ut < 3; ++ut) {
                    acc[ut].x = 0.f; acc[ut].y = 0.f; acc[ut].z = 0.f; acc[ut].w = 0.f;
                }
#pragma unroll
                for (int ut = 0; ut < 3; ++ut) {
                    const int k = t + ut;        // u-tile t+ut-1
                    acc[ut] = __builtin_amdgcn_mfma_f32_16x16x32_f16(a0[t], B0[k], acc[ut], 0, 0, 0);
                    acc[ut] = __builtin_amdgcn_mfma_f32_16x16x32_f16(a1[t], B1[k], acc[ut], 0, 0, 0);
                }
                // unconditional full-tile stores; t/ut/r are imm offsets
#pragma unroll
                for (int ut = 0; ut < 3; ++ut) {
#pragma unroll
                    for (int r = 0; r < 4; ++r) {
                        Lw[wb16 + t * 832 + r * 52 + ut * 16] = f2h(acc[ut][r]);
                    }
                }
            }
        }

        // readout for this di (wave-private LDS; no barrier needed)
        // 120 items = 20 dj x 6 w4-pairs; each item = one 16B ushort8 store.
        u16* outb = out + ((size_t)((b * 20 + di) * 20) * 64 + h) * 192;
#pragma unroll
        for (int it = 0; it < 2; ++it) {
            const int item = it * 64 + lane;
            if (item < 120) {
                const int dj = item / 6;
                const int p  = item - dj * 6;        // w4l = 2p, 2p+1
                ushort8_t o;
                if (valid) {
                    const int t  = p >> 1;           // (2p)>>2
                    const int wl = (p & 1) * 8;      // ((2p)&3)*4
                    const int base = t * 832 + wl * 53 + dj + 6;
                    o[0] = Lw[base];
                    o[1] = Lw[base + 53];
                    o[2] = Lw[base + 106];
                    o[3] = Lw[base + 159];
                    o[4] = Lw[base + 212];           // wl+4 block
                    o[5] = Lw[base + 265];
                    o[6] = Lw[base + 318];
                    o[7] = Lw[base + 371];
                } else {
                    o = (ushort8_t)0;
                }
                *(ushort8_t*)(outb + (size_t)dj * 12288 + (size_t)(wave * 48 + 8 * p)) = o;
            }
        }
    }
}

// ---------------------------------------------------------------------------
// Fused block v16: scalar row loads + generalized XCD swizzle (HT%8==0).
// Phase 1: batched load-pass + fdot2 compute-pass.
// Phase 2: f16 MFMA pointwise (stride-4 M-tile loop).
// ---------------------------------------------------------------------------
template<int CIN, int COUT, int S, int DT, int HH, int DIN, int HIN, int WIN,
         int DO, int HO, int WO, typename TOUT, bool SWZ = false>
static __device__ __forceinline__ void fused_impl(
        const u16* __restrict__ x,
        const float* __restrict__ dw_w, const float* __restrict__ dw_b,
        const float* __restrict__ pw_w, const float* __restrict__ pw_b,
        TOUT* __restrict__ y) {
    static_assert(WO % 48 == 0 && HO % HH == 0, "tile divisibility");
    constexpr int CINP = (CIN == 20) ? 22 : 42;    // odd dword stride
    constexpr int NTASK = CIN * 12;
    constexpr int WT = WO / 48;
    constexpr int HT = HO / HH;
    constexpr int NP = S * (DT - 1) + 3;
    constexpr int ROWS = S * (HH - 1) + 3;         // 6 or 9 (HH=4)
    constexpr int NL = (S == 1) ? 4 : 5;           // dwords per row
    constexpr int G  = (ROWS % 6 == 0) ? 6 : 3;    // rows per load batch
    constexpr int NG = ROWS / G;

    int wt, ht;
    if constexpr (SWZ) {
        // XCD band decode: XCD = blockIdx.x % 8 (y/z grid strides are
        // 0 mod 8). Each XCD owns HT/8 consecutive ht rows for all wt, so
        // h-halo rows between the band's tiles stay in the local L2.
        static_assert(HT % 8 == 0, "swz needs HT%8==0");
        constexpr int HPX = HT / 8;      // ht rows per xcd
        const int xx  = blockIdx.x;
        const int xcd = xx & 7;
        const int k   = xx >> 3;         // 0 .. WT*HPX-1
        ht = xcd * HPX + k / WT;
        wt = k - (k / WT) * WT;
    } else {
        wt = blockIdx.x % WT;
        ht = blockIdx.x / WT;
    }
    const int d0 = blockIdx.y * DT;
    const int b  = blockIdx.z;
    const int tid = threadIdx.x;
    const int h0 = ht * HH;
    const int wbase = wt * 48;

    __shared__ uint32_t sKW[CIN * 18];   // per ci: 9 taps x (KA,KB) half2
    __shared__ float    sDB[CIN];
    __shared__ u16      sT[DT * HH * 48 * CINP + 16];

    for (int i = tid; i < CIN * 9; i += 256) {
        const int ci = i / 9, t = i - ci * 9;
        const int kd = t / 3, kh = t - 3 * kd;
        const float k0 = dw_w[ci * 27 + kd * 9 + kh * 3 + 0];
        const float k1 = dw_w[ci * 27 + kd * 9 + kh * 3 + 1];
        const float k2 = dw_w[ci * 27 + kd * 9 + kh * 3 + 2];
        union { half2_t h; uint32_t u; } a, bb;
        a.h.x = (f16_t)k0; a.h.y = (f16_t)k1;
        if constexpr (S == 1) { bb.h.x = (f16_t)k2; bb.h.y = (f16_t)0.f; }
        else                  { bb.h.x = (f16_t)0.f; bb.h.y = (f16_t)k2; }
        sKW[ci * 18 + 2 * t]     = a.u;
        sKW[ci * 18 + 2 * t + 1] = bb.u;
    }
    for (int i = tid; i < CIN; i += 256) sDB[i] = dw_b[i];
    __syncthreads();

    // ---------------- phase 1: depthwise via fdot2 ----------------
    for (int idx = tid; idx < NTASK; idx += 256) {
        const int ci = idx / 12;
        const int wg = idx - ci * 12;
        const int w0g = wbase + wg * 4;
        const int offA = (w0g > 0) ? -2 : 0;   // keeps corner load in-bounds

        half2_t KA[9], KB[9];
#pragma unroll
        for (int t = 0; t < 9; ++t) {
            KA[t] = H2(sKW[ci * 18 + 2 * t]);       // broadcast across wg
            KB[t] = H2(sKW[ci * 18 + 2 * t + 1]);
        }

        float acc[DT][HH][4];
#pragma unroll
        for (int dl = 0; dl < DT; ++dl)
#pragma unroll
            for (int a = 0; a < HH; ++a)
#pragma unroll
                for (int c = 0; c < 4; ++c) acc[dl][a][c] = 0.f;

        const u16* plane0 = x + (size_t)(b * CIN + ci) * DIN * HIN * WIN;
#pragma unroll
        for (int p = 0; p < NP; ++p) {
            const int din = S * d0 - 1 + p;
            if (din < 0 || din >= DIN) continue;       // block-uniform, rare
            const u16* pl = plane0 + (size_t)din * HIN * WIN;
#pragma unroll
            for (int g = 0; g < NG; ++g) {
                // ---- load pass: all rows of this batch, unconditional ----
                uint32_t R[G][NL];
#pragma unroll
                for (int rr = 0; rr < G; ++rr) {
                    const int r = g * G + rr;
                    int hin = h0 * S - 1 + r;
                    int hc = hin < 0 ? 0 : (hin >= HIN ? HIN - 1 : hin);
                    const u16* rowp = pl + (size_t)hc * WIN + (size_t)w0g * S;
                    R[rr][0] = ldu(rowp + offA);
                    R[rr][1] = ldu(rowp);
                    R[rr][2] = ldu(rowp + 2);
                    R[rr][3] = ldu(rowp + 4);
                    if constexpr (S == 2) R[rr][4] = ldu(rowp + 6);
                }
                // ---- compute pass: masks + fdot2 ----
#pragma unroll
                for (int rr = 0; rr < G; ++rr) {
                    const int r = g * G + rr;
                    const int hin = h0 * S - 1 + r;
                    uint32_t D0 = R[rr][0], D1 = R[rr][1];
                    uint32_t D2 = R[rr][2], D3 = R[rr][3];
                    uint32_t E4 = 0;
                    if constexpr (S == 2) E4 = R[rr][4];
                    // w-edge masks (per-thread)
                    D0 = (w0g > 0) ? D0 : 0u;
                    if constexpr (S == 1) D3 = (w0g + 4 < WIN) ? D3 : 0u;
                    // h-validity: only boundary rows can be OOB.
                    if constexpr (S == 1) {
                        if (r == 0 || r == ROWS - 1) {
                            const bool rv = (hin >= 0) && (hin < HIN);
                            if (!rv) { D0 = 0; D1 = 0; D2 = 0; D3 = 0; }
                        }
                    } else {
                        if (r == 0) {
                            const bool rv = (hin >= 0);
                            if (!rv) { D0 = 0; D1 = 0; D2 = 0; D3 = 0; E4 = 0; }
                        }
                    }
                    uint32_t PA[4], PB[4];
                    if constexpr (S == 1) {
                        const uint32_t m01 = mkp(D0, D1);  // (x-1,x0)
                        const uint32_t m12 = mkp(D1, D2);  // (x1,x2)
                        const uint32_t m23 = mkp(D2, D3);  // (x3,x4)
                        PA[0] = m01; PA[1] = D1; PA[2] = m12; PA[3] = D2;
                        PB[0] = m12; PB[1] = D2; PB[2] = m23; PB[3] = D3;
                    } else {
                        PA[0] = mkp(D0, D1); PA[1] = mkp(D1, D2);
                        PA[2] = mkp(D2, D3); PA[3] = mkp(D3, E4);
                        PB[0] = D1; PB[1] = D2; PB[2] = D3; PB[3] = E4;
                    }
#pragma unroll
                    for (int dl = 0; dl < DT; ++dl) {
                        const int kd = p - S * dl;         // folds after unroll
                        if (kd < 0 || kd > 2) continue;
#pragma unroll
                        for (int hh = 0; hh < HH; ++hh) {
                            const int kh = r - S * hh;     // folds after unroll
                            if (kh < 0 || kh > 2) continue;
                            const int t = kd * 3 + kh;
#pragma unroll
                            for (int k = 0; k < 4; ++k)
                                acc[dl][hh][k] = FDOT2(H2(PB[k]), KB[t],
                                                 FDOT2(H2(PA[k]), KA[t],
                                                       acc[dl][hh][k]));
                        }
                    }
                }
            }
        }

        const float bia = sDB[ci];
#pragma unroll
        for (int dl = 0; dl < DT; ++dl) {
#pragma unroll
            for (int hh = 0; hh < HH; ++hh) {
#pragma unroll
                for (int k = 0; k < 4; ++k) {
                    const float t = acc[dl][hh][k] + bia;
                    sT[((dl * HH + hh) * 48 + wg * 4 + k) * CINP + ci] =
                        f2h(fmaxf(t, 0.1f * t));
                }
            }
        }
    }
    __syncthreads();

    // ---------------- phase 2: pointwise via f16 MFMA ----------------
    constexpr int NT = (COUT + 15) / 16;   // co tiles
    constexpr int KH = (CIN + 31) / 32;    // K=32 chunks
    constexpr int TOTAL_MT = DT * HH * 3;  // 16-wide M tiles
    const int lane = tid & 63, wave = tid >> 6;
    const int m15 = lane & 15, q = lane >> 4;

    half8_t bf[NT][KH];
    float   pb[NT];
#pragma unroll
    for (int nt = 0; nt < NT; ++nt) {
        const int co = nt * 16 + m15;
        pb[nt] = (co < COUT) ? pw_b[co] : 0.f;
#pragma unroll
        for (int kh = 0; kh < KH; ++kh) {
            union { half8_t v; f16_t e[8]; } u;
#pragma unroll
            for (int j = 0; j < 8; ++j) {
                const int ci = kh * 32 + q * 8 + j;
                u.e[j] = (co < COUT && ci < CIN)
                         ? (f16_t)pw_w[co * CIN + ci] : (f16_t)0.f;
            }
            bf[nt][kh] = u.v;
        }
    }

    const size_t planeSz = (size_t)DO * HO * WO;
    for (int mt = wave; mt < TOTAL_MT; mt += 4) {
        const int dl  = mt / (3 * HH);
        const int rem = mt - dl * 3 * HH;
        const int hh  = rem / 3;
        const int w0  = (rem - hh * 3) * 16;
        if (d0 + dl >= DO) continue;           // tail guard

        const int pos0 = (dl * HH + hh) * 48 + w0 + m15;
        const u16* ap = &sT[(size_t)pos0 * CINP];
        union { uint32_t u[4]; half8_t v; } af[KH];
#pragma unroll
        for (int kh = 0; kh < KH; ++kh) {
            const int ci0 = kh * 32 + q * 8;
            af[kh].u[0] = (ci0     < CIN) ? ldu(ap + ci0)     : 0u;
            af[kh].u[1] = (ci0 + 2 < CIN) ? ldu(ap + ci0 + 2) : 0u;
            af[kh].u[2] = (ci0 + 4 < CIN) ? ldu(ap + ci0 + 4) : 0u;
            af[kh].u[3] = (ci0 + 6 < CIN) ? ldu(ap + ci0 + 6) : 0u;
        }
#pragma unroll
        for (int nt = 0; nt < NT; ++nt) {
            f32x4 acc;
            acc.x = 0.f; acc.y = 0.f; acc.z = 0.f; acc.w = 0.f;
#pragma unroll
            for (int kh = 0; kh < KH; ++kh)
                acc = __builtin_amdgcn_mfma_f32_16x16x32_f16(
                          af[kh].v, bf[nt][kh], acc, 0, 0, 0);
            const int co = nt * 16 + m15;
            if (co < COUT) {
                const float bias = pb[nt];
                TOUT* yp = y + (size_t)b * COUT * planeSz + (size_t)co * planeSz
                             + (size_t)(d0 + dl) * HO * WO
                             + (size_t)(h0 + hh) * WO + wbase + w0 + q * 4;
                float s0 = acc.x + bias, s1 = acc.y + bias;
                float s2 = acc.z + bias, s3 = acc.w + bias;
                s0 = fmaxf(s0, 0.1f * s0); s1 = fmaxf(s1, 0.1f * s1);
                s2 = fmaxf(s2, 0.1f * s2); s3 = fmaxf(s3, 0.1f * s3);
                if constexpr (sizeof(TOUT) == 4) {
                    float4 o; o.x = s0; o.y = s1; o.z = s2; o.w = s3;
                    *(float4*)yp = o;
                } else {
                    ushort4 o;
                    o.x = f2h(s0); o.y = f2h(s1); o.z = f2h(s2); o.w = f2h(s3);
                    *(ushort4*)yp = o;
                }
            }
        }
    }
}

// Named wrappers -> per-stage visibility in rocprof.
__global__ __launch_bounds__(256) void fb1_dwpw(
        const u16* __restrict__ x, const float* __restrict__ dww,
        const float* __restrict__ dwb, const float* __restrict__ pww,
        const float* __restrict__ pwb, u16* __restrict__ y) {
    fused_impl<20, 20, 1, 4, 4, 20, 64, 192, 20, 64, 192, u16, true>(x, dww, dwb, pww, pwb, y);
}
__global__ __launch_bounds__(256) void fb2_dwpw(
        const u16* __restrict__ x, const float* __restrict__ dww,
        const float* __restrict__ dwb, const float* __restrict__ pww,
        const float* __restrict__ pwb, u16* __restrict__ y) {
    fused_impl<20, 40, 2, 2, 4, 20, 64, 192, 10, 32, 96, u16, true>(x, dww, dwb, pww, pwb, y);
}
__global__ __launch_bounds__(256) void fb3_dwpw(
        const u16* __restrict__ x, const float* __restrict__ dww,
        const float* __restrict__ dwb, const float* __restrict__ pww,
        const float* __restrict__ pwb, u16* __restrict__ y) {
    fused_impl<40, 40, 1, 2, 4, 10, 32, 96, 10, 32, 96, u16, true>(x, dww, dwb, pww, pwb, y);
}
__global__ __launch_bounds__(256) void fb4_dwpw(
        const u16* __restrict__ x, const float* __restrict__ dww,
        const float* __restrict__ dwb, const float* __restrict__ pww,
        const float* __restrict__ pwb, float* __restrict__ y) {
    fused_impl<40, 80, 2, 1, 4, 10, 32, 96, 5, 16, 48, float>(x, dww, dwb, pww, pwb, y);
}

// ---------------------------------------------------------------------------
extern "C" void kernel_launch(void* const* d_in, const int* in_sizes, int n_in,
                              void* d_out, int out_size, void* d_ws, size_t ws_size,
                              hipStream_t stream) {
    const float* rgb  = (const float*)d_in[0];
    const float* dep  = (const float*)d_in[1];
    const float* dw1w = (const float*)d_in[2];
    const float* dw1b = (const float*)d_in[3];
    const float* pw1w = (const float*)d_in[4];
    const float* pw1b = (const float*)d_in[5];
    const float* dw2w = (const float*)d_in[6];
    const float* dw2b = (const float*)d_in[7];
    const float* pw2w = (const float*)d_in[8];
    const float* pw2b = (const float*)d_in[9];
    const float* dw3w = (const float*)d_in[10];
    const float* dw3b = (const float*)d_in[11];
    const float* pw3w = (const float*)d_in[12];
    const float* pw3b = (const float*)d_in[13];
    const float* dw4w = (const float*)d_in[14];
    const float* dw4b = (const float*)d_in[15];
    const float* pw4w = (const float*)d_in[16];
    const float* pw4b = (const float*)d_in[17];

    const size_t HALF = 78643200;
    u16* corrO = (u16*)d_ws;
    u16* rgbT  = (u16*)((char*)d_ws + HALF);
    u16* depT  = (u16*)((char*)d_ws + HALF + 12582912);
    u16* b1o   = (u16*)((char*)d_ws + HALF);   // rgbT/depT dead by then
    u16* b2o   = (u16*)d_ws;                   // corrO dead by then
    u16* b3o   = (u16*)((char*)d_ws + HALF);   // b1o dead by then
    float* outp = (float*)d_out;

    transpose_f16<<<dim3(512, 2), 256, 0, stream>>>(rgb, dep, rgbT, depT);

    corr_mfma<<<dim3(2560), 256, 0, stream>>>(rgbT, depT, corrO);

    fb1_dwpw<<<dim3(64, 5, 8), 256, 0, stream>>>(corrO, dw1w, dw1b, pw1w, pw1b, b1o);
    fb2_dwpw<<<dim3(16, 5, 8), 256, 0, stream>>>(b1o, dw2w, dw2b, pw2w, pw2b, b2o);
    fb3_dwpw<<<dim3(16, 5, 8), 256, 0, stream>>>(b2o, dw3w, dw3b, pw3w, pw3b, b3o);
    fb4_dwpw<<<dim3(4, 5, 8), 256, 0, stream>>>(b3o, dw4w, dw4b, pw4w, pw4b, outp);
}